// Round 7
// baseline (578.673 us; speedup 1.0000x reference)
//
#include <hip/hip_runtime.h>
#include <hip/hip_bf16.h>

typedef __hip_bfloat16 bf16;
typedef unsigned short u16;
typedef _Float16 f16;
typedef f16 h2 __attribute__((ext_vector_type(2)));

#define D 128
#define EDIM 16
#define SQRT_D 11.313708498984761f

typedef short bf16x8 __attribute__((ext_vector_type(8)));
typedef float f32x4 __attribute__((ext_vector_type(4)));

// pf (prepped fp32 params) layout, in floats
#define PF_BL    0
#define PF_BR    128
#define PF_ATT   256
#define PF_BIAS  384
#define PF_GAMMA 512
#define PF_BETA  640
#define PF_TOTAL 768

__device__ __forceinline__ u16 f2bf_bits(float f) {
    union { bf16 h; u16 s; } cv; cv.h = __float2bfloat16(f); return cv.s;
}
__device__ __forceinline__ unsigned h2u(h2 h) {
    union { h2 h; unsigned u; } c; c.h = h; return c.u;
}
__device__ __forceinline__ h2 u2h(unsigned u) {
    union { unsigned u; h2 h; } c; c.u = u; return c.h;
}
__device__ __forceinline__ unsigned packh2(float a, float b) {
    h2 h; h[0] = (f16)a; h[1] = (f16)b; return h2u(h);
}
__device__ __forceinline__ float fdot2(h2 a, h2 b, float c) {
    return __builtin_amdgcn_fdot2(a, b, c, false);
}
// XOR-swizzled index for W^T bf16 tiles (conflict-free ds_read_b128)
__device__ __forceinline__ int swid(int nn, int k) {
    return nn * 128 + ((((k >> 3) ^ (nn & 15)) << 3) | (k & 7));
}
// 8-lane all-reduce sum via DPP (xor1, xor2, xor4 within row16)
__device__ __forceinline__ float red8(float x) {
    x += __int_as_float(__builtin_amdgcn_update_dpp(0, __float_as_int(x), 0xB1, 0xf, 0xf, true));
    x += __int_as_float(__builtin_amdgcn_update_dpp(0, __float_as_int(x), 0x4E, 0xf, 0xf, true));
    x += __int_as_float(__builtin_amdgcn_update_dpp(0, __float_as_int(x), 0x141, 0xf, 0xf, true));
    return x;
}
__device__ __forceinline__ float rdv(const void* p, int i, int fl) {
    return fl ? ((const float*)p)[i] : __bfloat162float(((const bf16*)p)[i]);
}
// per-block input dtype detect (1024 samples of emb's u16 halves)
__device__ __forceinline__ int block_detect(const u16* __restrict__ u) {
    __shared__ int flS;
    int t = threadIdx.x;
    if (t < 64) {
        int cnt = 0;
        #pragma unroll
        for (int k = 0; k < 16; ++k) {
            int e = (u[t * 16 + k] >> 7) & 0xFF;
            cnt += (e > 132 && e < 255) ? 1 : 0;
        }
        #pragma unroll
        for (int o = 32; o; o >>= 1) cnt += __shfl_xor(cnt, o, 64);
        if (t == 0) flS = cnt > 64 ? 1 : 0;
    }
    __syncthreads();
    return flS;
}

// ---------------------------------------------------------------- K0: zero
__global__ void k_zero(int* p, int count) {
    int i = blockIdx.x * blockDim.x + threadIdx.x;
    if (i < count) p[i] = 0;
}

// ------------- K1: prep (emb16, WT, weh, pf, ewh) + dst histogram (fused)
__global__ __launch_bounds__(256) void k_prep_hist(
    const void* emb, const void* Wl, const void* Wr, const void* bl,
    const void* br, const void* We, const void* att, const void* bias,
    const void* gamma, const void* beta, const void* ew,
    u16* __restrict__ emb16, u16* __restrict__ WT,
    unsigned* __restrict__ weh, float* __restrict__ pf,
    uint4* __restrict__ ewh,
    const int* __restrict__ ei, int* __restrict__ deg,
    int nE, int embCount, int histBlocks)
{
    if ((int)blockIdx.x < histBlocks) {
        int e = blockIdx.x * 256 + threadIdx.x;
        if (e < nE) atomicAdd(&deg[ei[nE + e]], 1);
        return;
    }
    const int fl = block_detect((const u16*)emb);
    int idx = (blockIdx.x - histBlocks) * 256 + threadIdx.x;
    if (idx < embCount) {
        emb16[idx] = f2bf_bits(rdv(emb, idx, fl) * SQRT_D);
        return;
    }
    idx -= embCount;
    if (idx < 32768) {              // W^T swizzled bf16 tiles
        int w = idx >> 14;
        int j = idx & 16383;
        int k = j >> 7, nn = j & 127;
        WT[w * 16384 + swid(nn, k)] = f2bf_bits(rdv(w ? Wr : Wl, k * D + nn, fl));
        return;
    }
    idx -= 32768;
    if (idx < 1024) {               // weh[q*128+ch] = (We[2q][ch], We[2q+1][ch]) f16
        int q = idx >> 7, ch = idx & 127;
        weh[idx] = packh2(rdv(We, (2 * q) * D + ch, fl),
                          rdv(We, (2 * q + 1) * D + ch, fl));
        return;
    }
    idx -= 1024;
    if (idx < 128) { pf[PF_BL + idx]    = rdv(bl, idx, fl);    return; }
    idx -= 128;
    if (idx < 128) { pf[PF_BR + idx]    = rdv(br, idx, fl);    return; }
    idx -= 128;
    if (idx < 128) { pf[PF_ATT + idx]   = rdv(att, idx, fl);   return; }
    idx -= 128;
    if (idx < 128) { pf[PF_BIAS + idx]  = rdv(bias, idx, fl);  return; }
    idx -= 128;
    if (idx < 128) { pf[PF_GAMMA + idx] = rdv(gamma, idx, fl); return; }
    idx -= 128;
    if (idx < 128) { pf[PF_BETA + idx]  = rdv(beta, idx, fl);  return; }
    idx -= 128;
    if (idx < nE) {                 // ewh: one edge row -> 16 f16 (2 uint4)
        float v[EDIM];
        #pragma unroll
        for (int k = 0; k < EDIM; ++k) v[k] = rdv(ew, idx * EDIM + k, fl);
        uint4 a, b;
        unsigned* ap = (unsigned*)&a; unsigned* bp = (unsigned*)&b;
        #pragma unroll
        for (int q = 0; q < 4; ++q) {
            ap[q] = packh2(v[2 * q],     v[2 * q + 1]);
            bp[q] = packh2(v[8 + 2 * q], v[8 + 2 * q + 1]);
        }
        ewh[(size_t)idx * 2]     = a;
        ewh[(size_t)idx * 2 + 1] = b;
    }
}

// ---------------- K2: block 0 = CSR scan; blocks 1.. = node MFMA transform
__global__ __launch_bounds__(256) void k_scan_node(
    const int* __restrict__ deg, int* __restrict__ row_ptr,
    int* __restrict__ cursor, int n,
    const int* __restrict__ x, const u16* __restrict__ emb16,
    const u16* __restrict__ WTg, const float* __restrict__ pf,
    u16* __restrict__ xl16, u16* __restrict__ xr16)
{
    __shared__ int part[256];
    __shared__ u16 Bt[2][16384];
    const int t = threadIdx.x;

    if (blockIdx.x == 0) {          // ---- CSR exclusive scan
        const int chunk = (n + 255) >> 8;
        const int beg = t * chunk;
        const int end = min(beg + chunk, n);
        int s = 0;
        for (int i = beg; i < end; ++i) s += deg[i];
        part[t] = s;
        __syncthreads();
        for (int off = 1; off < 256; off <<= 1) {
            int v = (t >= off) ? part[t - off] : 0;
            __syncthreads();
            part[t] += v;
            __syncthreads();
        }
        int run = (t > 0) ? part[t - 1] : 0;
        for (int i = beg; i < end; ++i) {
            row_ptr[i] = run;
            cursor[i] = run;
            run += deg[i];
        }
        if (t == 255) row_ptr[n] = part[255];
        return;
    }

    // ---- node transform: 64 rows per block, MFMA 16x16x32_bf16
    {   // stage both W^T tiles (64 KB), linear conflict-free copy
        const uint4* s = (const uint4*)WTg;
        uint4* dd = (uint4*)&Bt[0][0];
        #pragma unroll
        for (int i = 0; i < 16; ++i) dd[i * 256 + t] = s[i * 256 + t];
    }
    const int l = t & 63;
    const int wv = t >> 6;
    const int m = l & 15;
    const int quad = l >> 4;
    const int R = (blockIdx.x - 1) * 64;

    int arow = R + wv * 16 + m;
    int tok = (arow < n) ? x[arow] : 0;
    const u16* ap = emb16 + (size_t)tok * D + quad * 8;
    bf16x8 afr[4];
    #pragma unroll
    for (int kk = 0; kk < 4; ++kk) afr[kk] = *(const bf16x8*)(ap + kk * 32);
    __syncthreads();

    #pragma unroll
    for (int w = 0; w < 2; ++w) {
        const float* bb = pf + (w ? PF_BR : PF_BL);
        u16* out = w ? xr16 : xl16;
        f32x4 acc[8];
        #pragma unroll
        for (int nt = 0; nt < 8; ++nt) {
            float bv = bb[nt * 16 + m];
            acc[nt] = f32x4{bv, bv, bv, bv};
        }
        #pragma unroll
        for (int kk = 0; kk < 4; ++kk) {
            #pragma unroll
            for (int nt = 0; nt < 8; ++nt) {
                int blk = (quad + 4 * kk) ^ m;
                bf16x8 bfr = *(const bf16x8*)&Bt[w][(nt * 16 + m) * 128 + blk * 8];
                acc[nt] = __builtin_amdgcn_mfma_f32_16x16x32_bf16(afr[kk], bfr, acc[nt], 0, 0, 0);
            }
        }
        #pragma unroll
        for (int nt = 0; nt < 8; ++nt) {
            int col = nt * 16 + m;
            #pragma unroll
            for (int r = 0; r < 4; ++r) {
                int row = R + wv * 16 + quad * 4 + r;
                if (row < n) out[(size_t)row * D + col] = f2bf_bits(acc[nt][r]);
            }
        }
    }
}

// ------------------------- K3: CSR scatter (premultiplied byte offsets)
__global__ void k_scatter(const int* __restrict__ ei, int* __restrict__ cursor,
                          int2* __restrict__ csr, int nE)
{
    int e = blockIdx.x * blockDim.x + threadIdx.x;
    if (e < nE) {
        int src = ei[e], dst = ei[nE + e];
        int pos = atomicAdd(&cursor[dst], 1);
        csr[pos] = make_int2(src << 8, e << 5);   // xl row bytes, ewh bytes
    }
}

// -------------- K4: aggregation. 1 wave = 1 node (x2), 4-edge pipeline.
// lane l owns channels 2l, 2l+1 (head l>>3): 16 fdot2 + 3 DPP + 1 expf/edge.
__global__ __launch_bounds__(256) void k_agg(
    const int* __restrict__ row_ptr, const int2* __restrict__ csr,
    const uint4* __restrict__ ewh, const unsigned* __restrict__ weh,
    const float* __restrict__ pf,
    const unsigned* __restrict__ xl32, const unsigned* __restrict__ xr32,
    float* __restrict__ vpre, float* __restrict__ bnsum,
    float* __restrict__ bnsumsq, int n)
{
    const int t = threadIdx.x;
    const int l = t & 63;
    const int wv = t >> 6;

    h2 weA[8], weB[8];
    #pragma unroll
    for (int q = 0; q < 8; ++q) {
        weA[q] = u2h(weh[q * 128 + 2 * l]);
        weB[q] = u2h(weh[q * 128 + 2 * l + 1]);
    }
    const float2 attv  = *(const float2*)&pf[PF_ATT + 2 * l];
    const float2 biasv = *(const float2*)&pf[PF_BIAS + 2 * l];
    const char* xlB = (const char*)xl32 + 4 * l;
    const char* ewB = (const char*)ewh;

    float s0 = 0, s20 = 0, s1 = 0, s21 = 0;
    const int ibase = blockIdx.x * 8 + wv * 2;
    const int iend = min(ibase + 2, n);

    for (int i = ibase; i < iend; ++i) {
        const int beg = row_ptr[i], end = row_ptr[i + 1];
        const int cnt = end - beg;
        unsigned xru = xr32[(size_t)i * 64 + l];
        const float xr0 = __uint_as_float(xru << 16);
        const float xr1 = __uint_as_float(xru & 0xffff0000u);
        float acc0 = 0, acc1 = 0, den = 0;

        uint4 w0[4], w1[4];
        unsigned xp[4];
        int jf = beg;
        #pragma unroll
        for (int s = 0; s < 4; ++s) {
            if (s < cnt) {
                int2 c = csr[jf]; ++jf;
                xp[s] = *(const unsigned*)(xlB + c.x);
                const uint4* ep = (const uint4*)(ewB + c.y);
                w0[s] = ep[0]; w1[s] = ep[1];
            }
        }

        for (int done = 0; done < cnt; ) {
            int batch = min(4, cnt - done);
            #pragma unroll
            for (int s = 0; s < 4; ++s) {
                if (s < batch) {
                    union { uint4 u; h2 h[4]; } A, B;
                    A.u = w0[s]; B.u = w1[s];
                    unsigned xu = xp[s];
                    // refill slot s early (hide latency behind compute)
                    if (jf < end) {
                        int2 c = csr[jf]; ++jf;
                        xp[s] = *(const unsigned*)(xlB + c.x);
                        const uint4* ep = (const uint4*)(ewB + c.y);
                        w0[s] = ep[0]; w1[s] = ep[1];
                    }
                    float e0 = xr0, e1 = xr1;
                    #pragma unroll
                    for (int q = 0; q < 4; ++q) {
                        e0 = fdot2(A.h[q], weA[q], e0);
                        e1 = fdot2(A.h[q], weB[q], e1);
                    }
                    #pragma unroll
                    for (int q = 0; q < 4; ++q) {
                        e0 = fdot2(B.h[q], weA[4 + q], e0);
                        e1 = fdot2(B.h[q], weB[4 + q], e1);
                    }
                    float x0 = __uint_as_float(xu << 16);
                    float x1 = __uint_as_float(xu & 0xffff0000u);
                    float z0 = x0 + e0, z1 = x1 + e1;
                    float m0 = fmaxf(z0, 0.2f * z0);     // leaky_relu 0.2
                    float m1 = fmaxf(z1, 0.2f * z1);
                    float p = red8(fmaf(m1, attv.y, m0 * attv.x));
                    float ex = __expf(p);
                    den += ex;
                    acc0 = fmaf(ex, x0, acc0);
                    acc1 = fmaf(ex, x1, acc1);
                }
            }
            done += batch;
        }

        float inv = den > 0.f ? 1.0f / den : 0.0f;
        float v0 = acc0 * inv + biasv.x;
        float v1 = acc1 * inv + biasv.y;
        *(float2*)(vpre + (size_t)i * D + 2 * l) = make_float2(v0, v1);
        s0 += v0; s20 += v0 * v0;
        s1 += v1; s21 += v1 * v1;
    }

    __shared__ float sh[4][D], sh2[4][D];
    sh[wv][2 * l] = s0;   sh[wv][2 * l + 1] = s1;
    sh2[wv][2 * l] = s20; sh2[wv][2 * l + 1] = s21;
    __syncthreads();
    if (t < D) {
        float a = 0, a2 = 0;
        #pragma unroll
        for (int q = 0; q < 4; ++q) { a += sh[q][t]; a2 += sh2[q][t]; }
        atomicAdd(&bnsum[t], a);
        atomicAdd(&bnsumsq[t], a2);
    }
}

// ------------------------------------------------------------- K5: finalize
__global__ __launch_bounds__(256) void k_final(
    const float* __restrict__ vpre, const float* __restrict__ pf,
    const float* __restrict__ bnsum, const float* __restrict__ bnsumsq,
    float* __restrict__ out, int n)
{
    int idx = blockIdx.x * 256 + threadIdx.x;
    if (idx >= n * (D / 4)) return;
    int pos = idx * 4;
    int d = pos & (D - 1);
    const float invN = 1.0f / (float)n;
    float4 v  = *(const float4*)(vpre + pos);
    float4 ms = *(const float4*)(bnsum + d);
    float4 m2 = *(const float4*)(bnsumsq + d);
    float4 g  = *(const float4*)(pf + PF_GAMMA + d);
    float4 bt = *(const float4*)(pf + PF_BETA + d);
    float* vv = (float*)&v; float* msv = (float*)&ms; float* m2v = (float*)&m2;
    float* gv = (float*)&g; float* btv = (float*)&bt;
    float4 o; float* ov = (float*)&o;
    #pragma unroll
    for (int c = 0; c < 4; ++c) {
        float mean = msv[c] * invN;
        float var = m2v[c] * invN - mean * mean;
        float y = (vv[c] - mean) * rsqrtf(var + 1e-5f) * gv[c] + btv[c];
        ov[c] = y > 0.f ? y : 0.01f * y;          // leaky_relu 0.01
    }
    *(float4*)(out + pos) = o;
}

// ---------------------------------------------------------------- launch
extern "C" void kernel_launch(void* const* d_in, const int* in_sizes, int n_in,
                              void* d_out, int out_size, void* d_ws, size_t ws_size,
                              hipStream_t stream)
{
    const int*  x     = (const int*)d_in[0];
    const int*  ei    = (const int*)d_in[1];
    const void* ew    = d_in[2];
    const void* emb   = d_in[3];
    const void* Wl    = d_in[4];
    const void* bl    = d_in[5];
    const void* Wr    = d_in[6];
    const void* br    = d_in[7];
    const void* att   = d_in[8];
    const void* We    = d_in[9];
    const void* bias  = d_in[10];
    const void* gamma = d_in[11];
    const void* beta  = d_in[12];

    const int n  = in_sizes[0];
    const int nE = in_sizes[1] / 2;
    const int embCount = in_sizes[3];

    // ws layout
    float* ws      = (float*)d_ws;
    float* vpre    = ws;                               // n*128 f32
    u16*   xl16    = (u16*)(vpre + (size_t)n * D);     // n*128 u16
    u16*   xr16    = xl16 + (size_t)n * D;
    int*   deg     = (int*)(xr16 + (size_t)n * D);
    float* bnsum   = (float*)(deg + n);
    float* bnsumsq = bnsum + D;
    int*   row_ptr = (int*)(bnsumsq + D);
    int*   cursor  = row_ptr + (n + 1);
    uintptr_t p    = (uintptr_t)(cursor + n);
    p = (p + 15) & ~(uintptr_t)15;
    int2*  csr     = (int2*)p;
    p = (uintptr_t)(csr + nE);
    p = (p + 15) & ~(uintptr_t)15;
    uint4* ewh     = (uint4*)p;                        // nE*2 uint4
    u16*   emb16   = (u16*)(ewh + (size_t)nE * 2);
    u16*   WT      = emb16 + embCount;
    unsigned* weh  = (unsigned*)(WT + 32768);
    float* pf      = (float*)(weh + 1024);

    int zc = n + 2 * D;
    k_zero<<<(zc + 255) / 256, 256, 0, stream>>>(deg, zc);

    int histBlocks = (nE + 255) / 256;
    int prepN = embCount + 32768 + 1024 + 6 * 128 + nE;
    int prepBlocks = (prepN + 255) / 256;
    k_prep_hist<<<histBlocks + prepBlocks, 256, 0, stream>>>(
        emb, Wl, Wr, bl, br, We, att, bias, gamma, beta, ew,
        emb16, WT, weh, pf, ewh, ei, deg, nE, embCount, histBlocks);

    int nodeBlocks = (n + 63) / 64;
    k_scan_node<<<1 + nodeBlocks, 256, 0, stream>>>(
        deg, row_ptr, cursor, n, x, emb16, WT, pf, xl16, xr16);

    k_scatter<<<histBlocks, 256, 0, stream>>>(ei, cursor, csr, nE);

    k_agg<<<(n + 7) / 8, 256, 0, stream>>>(
        row_ptr, csr, ewh, weh, pf,
        (const unsigned*)xl16, (const unsigned*)xr16,
        vpre, bnsum, bnsumsq, n);

    k_final<<<(n * (D / 4) + 255) / 256, 256, 0, stream>>>(
        vpre, pf, bnsum, bnsumsq, (float*)d_out, n);
}